// Round 1
// 155.269 us; speedup vs baseline: 1.0088x; 1.0088x over previous
//
#include <hip/hip_runtime.h>

// Problem constants (from reference):
constexpr int kB    = 32;
constexpr int kTin  = 512;
constexpr int kTout = 2048;
constexpr int kA    = 384;    // ADIM
constexpr int kC4   = kA / 4; // 96 float4 per row
constexpr int kBPB  = 32;               // blocks per batch
constexpr int kRPB  = kTout / kBPB;     // 64 output rows per block
constexpr int kSegs = kTin / 64;        // 8 wave-scan segments

typedef float vf4 __attribute__((ext_vector_type(4)));

// ---------------------------------------------------------------------------
// Single fused kernel: per-block wave-scan of the batch's masked durations
// (replaces the old 18-barrier Hillis-Steele kernel A), 64-thread binary
// search for this block's 64-row window, then the register-resident
// pointwise gather + pitch/energy embed + bias loop (unchanged math).
// Grid: 32 batches x 32 slots = 1024 blocks, 384 threads.
// ---------------------------------------------------------------------------
__global__ __launch_bounds__(384) void fused_va_kernel(
    const float* __restrict__ hs,            // [B, T_IN, ADIM]
    const int*   __restrict__ durations,     // [B, T_IN]
    const int*   __restrict__ input_lengths, // [B]
    const vf4*   __restrict__ pitch_t,       // [B*T_OUT] (PDIM=4 packed)
    const float* __restrict__ energy_t,      // [B*T_OUT] (EDIM=1)
    const vf4*   __restrict__ pitch_w,       // [ADIM] rows of 4
    const float* __restrict__ pitch_b,       // [ADIM]
    const float* __restrict__ energy_w,      // [ADIM]
    const float* __restrict__ energy_b,      // [ADIM]
    float*       __restrict__ out)           // [B*T_OUT*ADIM]
{
    __shared__ int cum[kTin];        // segment-local inclusive scans
    __shared__ int ssum[kSegs];      // per-segment totals
    __shared__ int soff[kSegs + 1];  // exclusive scan of segment totals (+grand total)
    __shared__ int ridx[kRPB];       // source phone per output row in this window

    const int tid  = threadIdx.x;
    const int b    = blockIdx.x / kBPB;
    const int slot = blockIdx.x % kBPB;
    const int row0 = slot * kRPB;    // window start within batch

    const int len  = input_lengths[b];
    const int wave = tid >> 6;
    const int lane = tid & 63;

    // --- masked-duration scan: 8 segments of 64 lanes, 6 waves (2 do double duty)
    for (int seg = wave; seg < kSegs; seg += 384 / 64) {
        const int i = (seg << 6) + lane;
        int dv = (i < len) ? durations[b * kTin + i] : 0;
        #pragma unroll
        for (int off = 1; off < 64; off <<= 1) {
            const int n = __shfl_up(dv, off, 64);
            if (lane >= off) dv += n;
        }
        cum[i] = dv;
        if (lane == 63) ssum[seg] = dv;
    }
    __syncthreads();
    if (tid == 0) {
        int s = 0;
        #pragma unroll
        for (int k = 0; k < kSegs; ++k) { soff[k] = s; s += ssum[k]; }
        soff[kSegs] = s;
    }
    __syncthreads();
    const int total = soff[kSegs];

    // --- resolve this window's 64 source indices (searchsorted right) ---
    if (tid < kRPB) {
        const int to = row0 + tid;
        int r = -1;
        if (total == 0) {
            // reference refills masked positions with ones: cum[i]=min(i+1,len)
            // => searchsorted gives idx=t for t<len; frames t>=len are masked.
            if (to < len) r = to;
        } else if (to < total) {
            int lo = 0, hi = kTin;
            while (lo < hi) {
                const int mid = (lo + hi) >> 1;
                if (cum[mid] + soff[mid >> 6] <= to) lo = mid + 1; else hi = mid;
            }
            r = (lo < kTin) ? lo : (kTin - 1);
        }
        ridx[tid] = r;
    }
    __syncthreads();

    // --- pointwise fuse loop: thread owns channel quad c4, 4 rows/iter ---
    const int c4 = tid % kC4;
    const int sub = tid / kC4;
    const int a0 = c4 * 4;

    const vf4 w0 = pitch_w[a0];
    const vf4 w1 = pitch_w[a0 + 1];
    const vf4 w2 = pitch_w[a0 + 2];
    const vf4 w3 = pitch_w[a0 + 3];
    const vf4 ew = { energy_w[a0], energy_w[a0 + 1],
                     energy_w[a0 + 2], energy_w[a0 + 3] };
    const vf4 bias = { pitch_b[a0]     + energy_b[a0],
                       pitch_b[a0 + 1] + energy_b[a0 + 1],
                       pitch_b[a0 + 2] + energy_b[a0 + 2],
                       pitch_b[a0 + 3] + energy_b[a0 + 3] };

    const long rowbase = (long)b * kTout + row0;
    #pragma unroll 4
    for (int it = 0; it < kRPB / 4; ++it) {
        const int  rl  = (it << 2) + sub;
        const long row = rowbase + rl;
        const int  src = ridx[rl];
        vf4 h = { 0.f, 0.f, 0.f, 0.f };
        if (src >= 0)
            h = *(const vf4*)(hs + ((long)b * kTin + src) * kA + a0);
        const vf4   pt = pitch_t[row];
        const float e  = energy_t[row];
        vf4 o;
        o.x = h.x + pt.x * w0.x + pt.y * w0.y + pt.z * w0.z + pt.w * w0.w + e * ew.x + bias.x;
        o.y = h.y + pt.x * w1.x + pt.y * w1.y + pt.z * w1.z + pt.w * w1.w + e * ew.y + bias.y;
        o.z = h.z + pt.x * w2.x + pt.y * w2.y + pt.z * w2.z + pt.w * w2.w + e * ew.z + bias.z;
        o.w = h.w + pt.x * w3.x + pt.y * w3.y + pt.z * w3.z + pt.w * w3.w + e * ew.w + bias.w;
        // Output is never re-read: nontemporal store keeps the x4-reused hs
        // resident in L2 instead of being evicted by 100 MB of stream writes.
        __builtin_nontemporal_store(o, (vf4*)(out + row * kA + a0));
    }
}

extern "C" void kernel_launch(void* const* d_in, const int* in_sizes, int n_in,
                              void* d_out, int out_size, void* d_ws, size_t ws_size,
                              hipStream_t stream) {
    // setup_inputs() order:
    // 0 hs[32,512,384] f32 | 1 durations[32,512] int | 2 input_lengths[32] int
    // 3 pitch_target[32,2048,4] f32 | 4 energy_target[32,2048,1] f32
    // 5 duration_mask (unused) | 6 variance_mask (unused)
    // 7 pitch_w[384,4] f32 | 8 pitch_b[384] f32 | 9 energy_w[384,1] f32 | 10 energy_b[384] f32
    const float* hs            = (const float*)d_in[0];
    const int*   durations     = (const int*)d_in[1];
    const int*   input_lengths = (const int*)d_in[2];
    const float* pitch_t       = (const float*)d_in[3];
    const float* energy_t      = (const float*)d_in[4];
    const float* pitch_w       = (const float*)d_in[7];
    const float* pitch_b       = (const float*)d_in[8];
    const float* energy_w      = (const float*)d_in[9];
    const float* energy_b      = (const float*)d_in[10];
    float* out = (float*)d_out;

    fused_va_kernel<<<kB * kBPB, 384, 0, stream>>>(
        hs, durations, input_lengths,
        (const vf4*)pitch_t, energy_t,
        (const vf4*)pitch_w, pitch_b, energy_w, energy_b,
        out);
}